// Round 1
// baseline (1128.100 us; speedup 1.0000x reference)
//
#include <hip/hip_runtime.h>

typedef float v4f __attribute__((ext_vector_type(4)));

// Problem constants (from reference)
constexpr int B = 256;        // batch
constexpr int T = 64;         // trees
constexpr int C = 1000;       // mask columns (idx domain)
constexpr int F = 16080;      // output feature width
constexpr int K = 200;        // top-k
constexpr int F4 = F / 4;     // 4020 float4 per row
constexpr int C4 = C / 4;     // 250 float4 with possible nonzeros

// Kernel 1: one block per tree. Zero the attention row, find top-200 of the
// mask row via bitonic sort of packed keys in LDS, scatter sigmoid values.
// Key = (monotone(float_bits) << 32) | ~index  -> descending sort gives
// values descending, ties broken by lower index (matches lax.top_k).
__global__ __launch_bounds__(256) void topk_scatter_kernel(
    const float* __restrict__ mask, float* __restrict__ attn) {
  const int t = blockIdx.x;
  const int tid = threadIdx.x;
  __shared__ unsigned long long keys[1024];

  const float* row = mask + (size_t)t * C;
  float* arow = attn + (size_t)t * F;

  // load + pack keys (pad to 1024 with key=0, sorts last in descending order)
  for (int i = tid; i < 1024; i += 256) {
    if (i < C) {
      unsigned ub = __float_as_uint(row[i]);
      unsigned mono = (ub & 0x80000000u) ? ~ub : (ub | 0x80000000u);
      keys[i] = ((unsigned long long)mono << 32) | (unsigned)(~i);
    } else {
      keys[i] = 0ull;
    }
  }
  // zero the attention output row while keys land
  for (int i = tid; i < F; i += 256) arow[i] = 0.0f;
  __syncthreads();

  // bitonic sort, descending
  for (int k = 2; k <= 1024; k <<= 1) {
    for (int j = k >> 1; j > 0; j >>= 1) {
      for (int ii = tid; ii < 1024; ii += 256) {
        int l = ii ^ j;
        if (l > ii) {
          unsigned long long a = keys[ii];
          unsigned long long b2 = keys[l];
          bool sw = ((ii & k) == 0) ? (a < b2) : (a > b2);
          if (sw) { keys[ii] = b2; keys[l] = a; }
        }
      }
      __syncthreads();
    }
  }

  // scatter top-200: attn[t, idx] = sigmoid(value)
  if (tid < K) {
    unsigned long long key = keys[tid];
    unsigned idx = ~(unsigned)(key & 0xFFFFFFFFull);
    unsigned mono = (unsigned)(key >> 32);
    unsigned bits = (mono & 0x80000000u) ? (mono ^ 0x80000000u) : ~mono;
    float v = __uint_as_float(bits);
    float s = 1.0f / (1.0f + expf(-v));
    arow[idx] = s;
  }
}

// Kernel 2: one block per (b, t) output row of 16080 floats.
// Cols [0,1000): x[b,c] * attn[t,c].  Cols [1000,16080): exactly zero
// (attention can only be nonzero where idx < 1000), so no x read needed.
// Nontemporal stores: the 1 GB output is streaming; keep x/attn in L2.
__global__ __launch_bounds__(256) void outer_kernel(
    const float* __restrict__ x, const float* __restrict__ attn,
    float* __restrict__ out) {
  const int p = blockIdx.x;       // p = b*64 + t, matches output row order
  const int b = p >> 6;
  const int t = p & 63;
  const int tid = threadIdx.x;

  const v4f* x4 = (const v4f*)(x + (size_t)b * F);
  const v4f* a4 = (const v4f*)(attn + (size_t)t * F);
  v4f* o4 = (v4f*)(out + (size_t)p * F);

  if (tid < C4) {
    v4f r = x4[tid] * a4[tid];
    __builtin_nontemporal_store(r, o4 + tid);
  }
  v4f z = {0.0f, 0.0f, 0.0f, 0.0f};
  for (int i = C4 + tid; i < F4; i += 256) {
    __builtin_nontemporal_store(z, o4 + i);
  }
}

extern "C" void kernel_launch(void* const* d_in, const int* in_sizes, int n_in,
                              void* d_out, int out_size, void* d_ws, size_t ws_size,
                              hipStream_t stream) {
  const float* x = (const float*)d_in[0];          // (256,120,134) -> (256,16080)
  const float* mask = (const float*)d_in[1];       // (64,1000)
  float* out = (float*)d_out;                      // return_value (256,64,16080)
  float* attn = out + (size_t)B * T * F;           // attention (64,16080), 2nd output

  // attention first (outer_kernel reads it; same stream -> ordered)
  topk_scatter_kernel<<<T, 256, 0, stream>>>(mask, attn);
  outer_kernel<<<B * T, 256, 0, stream>>>(x, attn, out);
}

// Round 2
// 1075.217 us; speedup vs baseline: 1.0492x; 1.0492x over previous
//
#include <hip/hip_runtime.h>

typedef float v4f __attribute__((ext_vector_type(4)));

// Problem constants (from reference)
constexpr int B = 256;        // batch
constexpr int T = 64;         // trees
constexpr int C = 1000;       // mask columns (idx domain)
constexpr int F = 16080;      // output feature width
constexpr int K = 200;        // top-k
constexpr int F4 = F / 4;     // 4020 float4 per row
constexpr int C4 = C / 4;     // 250 float4 with possible nonzeros

// Kernel 1: one block per tree. Zero the attention row, find top-200 of the
// mask row via bitonic sort of packed keys in LDS, scatter sigmoid values.
// Key = (monotone(float_bits) << 32) | ~index  -> descending sort gives
// values descending, ties broken by lower index (matches lax.top_k).
__global__ __launch_bounds__(256) void topk_scatter_kernel(
    const float* __restrict__ mask, float* __restrict__ attn) {
  const int t = blockIdx.x;
  const int tid = threadIdx.x;
  __shared__ unsigned long long keys[1024];

  const float* row = mask + (size_t)t * C;
  float* arow = attn + (size_t)t * F;

  // load + pack keys (pad to 1024 with key=0, sorts last in descending order)
  for (int i = tid; i < 1024; i += 256) {
    if (i < C) {
      unsigned ub = __float_as_uint(row[i]);
      unsigned mono = (ub & 0x80000000u) ? ~ub : (ub | 0x80000000u);
      keys[i] = ((unsigned long long)mono << 32) | (unsigned)(~i);
    } else {
      keys[i] = 0ull;
    }
  }
  // zero the attention output row while keys land
  for (int i = tid; i < F; i += 256) arow[i] = 0.0f;
  __syncthreads();

  // bitonic sort, descending
  for (int k = 2; k <= 1024; k <<= 1) {
    for (int j = k >> 1; j > 0; j >>= 1) {
      for (int ii = tid; ii < 1024; ii += 256) {
        int l = ii ^ j;
        if (l > ii) {
          unsigned long long a = keys[ii];
          unsigned long long b2 = keys[l];
          bool sw = ((ii & k) == 0) ? (a < b2) : (a > b2);
          if (sw) { keys[ii] = b2; keys[l] = a; }
        }
      }
      __syncthreads();
    }
  }

  // scatter top-200: attn[t, idx] = sigmoid(value)
  if (tid < K) {
    unsigned long long key = keys[tid];
    unsigned idx = ~(unsigned)(key & 0xFFFFFFFFull);
    unsigned mono = (unsigned)(key >> 32);
    unsigned bits = (mono & 0x80000000u) ? (mono ^ 0x80000000u) : ~mono;
    float v = __uint_as_float(bits);
    float s = 1.0f / (1.0f + expf(-v));
    arow[idx] = s;
  }
}

// Kernel 2: one block per (b, t) output row of 16080 floats.
// Cols [0,1000): x[b,c] * attn[t,c].  Cols [1000,16080): exactly zero
// (attention can only be nonzero where idx < 1000), so no x read needed.
// PLAIN stores (not nontemporal): L2 write-combining is what lets the
// rocclr fill kernel hit 78% of HBM peak; nt bypasses it (round-1 lesson:
// nt stores ran at ~0.94 TB/s vs 6.27 TB/s for cached stores).
__global__ __launch_bounds__(256) void outer_kernel(
    const float* __restrict__ x, const float* __restrict__ attn,
    float* __restrict__ out) {
  const int p = blockIdx.x;       // p = b*64 + t, matches output row order
  const int b = p >> 6;
  const int t = p & 63;
  const int tid = threadIdx.x;

  const v4f* x4 = (const v4f*)(x + (size_t)b * F);
  const v4f* a4 = (const v4f*)(attn + (size_t)t * F);
  v4f* o4 = (v4f*)(out + (size_t)p * F);

  if (tid < C4) {
    o4[tid] = x4[tid] * a4[tid];
  }
  const v4f z = {0.0f, 0.0f, 0.0f, 0.0f};
  for (int i = C4 + tid; i < F4; i += 256) {
    o4[i] = z;
  }
}

extern "C" void kernel_launch(void* const* d_in, const int* in_sizes, int n_in,
                              void* d_out, int out_size, void* d_ws, size_t ws_size,
                              hipStream_t stream) {
  const float* x = (const float*)d_in[0];          // (256,120,134) -> (256,16080)
  const float* mask = (const float*)d_in[1];       // (64,1000)
  float* out = (float*)d_out;                      // return_value (256,64,16080)
  float* attn = out + (size_t)B * T * F;           // attention (64,16080), 2nd output

  // attention first (outer_kernel reads it; same stream -> ordered)
  topk_scatter_kernel<<<T, 256, 0, stream>>>(mask, attn);
  outer_kernel<<<B * T, 256, 0, stream>>>(x, attn, out);
}

// Round 3
// 1070.241 us; speedup vs baseline: 1.0541x; 1.0046x over previous
//
#include <hip/hip_runtime.h>

typedef float v4f __attribute__((ext_vector_type(4)));

// Problem constants (from reference)
constexpr int B = 256;        // batch
constexpr int T = 64;         // trees
constexpr int C = 1000;       // mask columns (idx domain)
constexpr int F = 16080;      // output feature width
constexpr int K = 200;        // top-k
constexpr int F4 = F / 4;     // 4020 float4 per row
constexpr int C4 = C / 4;     // 250 float4 with possible nonzeros
constexpr unsigned N4 = (unsigned)B * T * F4;  // 65,863,680 float4s in return_value

// Kernel 1: one block per tree. Zero the attention row, find top-200 of the
// mask row via bitonic sort of packed keys in LDS, scatter sigmoid values.
// Key = (monotone(float_bits) << 32) | ~index  -> descending sort gives
// values descending, ties broken by lower index (matches lax.top_k).
__global__ __launch_bounds__(256) void topk_scatter_kernel(
    const float* __restrict__ mask, float* __restrict__ attn) {
  const int t = blockIdx.x;
  const int tid = threadIdx.x;
  __shared__ unsigned long long keys[1024];

  const float* row = mask + (size_t)t * C;
  float* arow = attn + (size_t)t * F;

  // load + pack keys (pad to 1024 with key=0, sorts last in descending order)
  for (int i = tid; i < 1024; i += 256) {
    if (i < C) {
      unsigned ub = __float_as_uint(row[i]);
      unsigned mono = (ub & 0x80000000u) ? ~ub : (ub | 0x80000000u);
      keys[i] = ((unsigned long long)mono << 32) | (unsigned)(~i);
    } else {
      keys[i] = 0ull;
    }
  }
  // zero the attention output row (vectorized) while keys land
  {
    v4f* arow4 = (v4f*)arow;
    const v4f z = {0.0f, 0.0f, 0.0f, 0.0f};
    for (int i = tid; i < F4; i += 256) arow4[i] = z;
  }
  __syncthreads();

  // bitonic sort, descending
  for (int k = 2; k <= 1024; k <<= 1) {
    for (int j = k >> 1; j > 0; j >>= 1) {
      for (int ii = tid; ii < 1024; ii += 256) {
        int l = ii ^ j;
        if (l > ii) {
          unsigned long long a = keys[ii];
          unsigned long long b2 = keys[l];
          bool sw = ((ii & k) == 0) ? (a < b2) : (a > b2);
          if (sw) { keys[ii] = b2; keys[l] = a; }
        }
      }
      __syncthreads();
    }
  }

  // scatter top-200: attn[t, idx] = sigmoid(value)
  if (tid < K) {
    unsigned long long key = keys[tid];
    unsigned idx = ~(unsigned)(key & 0xFFFFFFFFull);
    unsigned mono = (unsigned)(key >> 32);
    unsigned bits = (mono & 0x80000000u) ? (mono ^ 0x80000000u) : ~mono;
    float v = __uint_as_float(bits);
    float s = 1.0f / (1.0f + expf(-v));
    arow[idx] = s;
  }
}

// Kernel 2: flat grid-stride sweep over ALL return_value float4s — the exact
// store-stream shape of the rocclr fill kernel that hits 79% of HBM peak on
// this buffer (round-2 lesson: 16384 tiny per-row blocks ran at only
// ~2.7 TB/s; per-block ramp-up + too few outstanding stores).
// quad i: p = i/4020 (magic-mul), c = i%4020; b=p>>6, t=p&63.
// c < 250  -> x[b,:1000]*attn[t,:1000] (both L2-resident, 4KB/row)
// c >= 250 -> exactly zero (attention has no nonzeros past col 999).
__global__ __launch_bounds__(256) void flat_outer_kernel(
    const float* __restrict__ x, const float* __restrict__ attn,
    float* __restrict__ out) {
  const v4f* __restrict__ x4 = (const v4f*)x;
  const v4f* __restrict__ a4 = (const v4f*)attn;
  v4f* __restrict__ o4 = (v4f*)out;

  const unsigned stride = gridDim.x * 256u;
  for (unsigned i = blockIdx.x * 256u + threadIdx.x; i < N4; i += stride) {
    unsigned p = i / (unsigned)F4;          // compiler magic-mul
    unsigned c = i - p * (unsigned)F4;
    v4f v = {0.0f, 0.0f, 0.0f, 0.0f};
    if (c < (unsigned)C4) {
      unsigned b = p >> 6;
      unsigned t = p & 63u;
      v = x4[b * (unsigned)F4 + c] * a4[t * (unsigned)F4 + c];
    }
    o4[i] = v;
  }
}

extern "C" void kernel_launch(void* const* d_in, const int* in_sizes, int n_in,
                              void* d_out, int out_size, void* d_ws, size_t ws_size,
                              hipStream_t stream) {
  const float* x = (const float*)d_in[0];          // (256,120,134) -> (256,16080)
  const float* mask = (const float*)d_in[1];       // (64,1000)
  float* out = (float*)d_out;                      // return_value (256,64,16080)
  float* attn = out + (size_t)B * T * F;           // attention (64,16080), 2nd output

  // attention first (flat_outer_kernel reads it; same stream -> ordered)
  topk_scatter_kernel<<<T, 256, 0, stream>>>(mask, attn);
  // 8192 blocks x 256 threads: ~31 uniform iterations/thread, linear sweep
  flat_outer_kernel<<<8192, 256, 0, stream>>>(x, attn, out);
}